// Round 4
// baseline (2736.411 us; speedup 1.0000x reference)
//
#include <hip/hip_runtime.h>

// ---------------- ws layout (float offsets) ----------------
// [0]        : dtype flag (int: 1 = bf16 inputs, 0 = fp32 inputs)
// O_WC       : Wc = W1 @ W_enc   [64][128] fp32
// O_BC       : bc = W1 @ b_enc   [64] fp32
// O_BIAS     : bias = b_ih+b_hh  [1024] fp32
// O_BLEND1   : blend1 [1024][50][64] fp32
// O_WB       : hi/lo bf16 weight region (ushort), right after blend1
#define O_WC     16
#define O_BC     (16 + 8192)
#define O_BIAS   (O_BC + 64)
#define O_BLEND1 16384
#define O_WB     3293184        // = 16384 + 1024*50*64
#define NEG_INF_V (-1.0e9f)

// ushort offsets inside the O_WB region
#define WB_HH_HI 0
#define WB_HH_LO 262144
#define WB_IH_HI 524288
#define WB_IH_LO 655360
#define WB_W2_HI 786432
#define WB_W2_LO 802816

using bf16x8 = __attribute__((ext_vector_type(8))) __bf16;
using f32x4  = __attribute__((ext_vector_type(4))) float;

__device__ __forceinline__ f32x4 mfma16(bf16x8 a, bf16x8 b, f32x4 c) {
  return __builtin_amdgcn_mfma_f32_16x16x32_bf16(a, b, c, 0, 0, 0);
}

__device__ __forceinline__ float b2f(unsigned int u) {
  union { unsigned int i; float f; } x; x.i = u << 16; return x.f;
}
__device__ __forceinline__ unsigned short f2b(float f) {
  union { float f; unsigned int i; } x; x.f = f;
  unsigned int r = x.i + 0x7fffu + ((x.i >> 16) & 1u);
  return (unsigned short)(r >> 16);
}
__device__ __forceinline__ float ldv(const void* p, int b16, long long i) {
  if (b16) return b2f(((const unsigned short*)p)[i]);
  return ((const float*)p)[i];
}
__device__ __forceinline__ float sigm(float x)  { return 1.0f / (1.0f + __expf(-x)); }
__device__ __forceinline__ float tanhx(float x) { return 1.0f - 2.0f / (1.0f + __expf(2.0f * x)); }

// select bf16 element e (0..7) out of a uint4, e must be unroll-constant
__device__ __forceinline__ float bfsel(const uint4& u, int e) {
  unsigned int w = (e < 2) ? u.x : (e < 4) ? u.y : (e < 6) ? u.z : u.w;
  union { unsigned int i; float f; } x;
  x.i = (e & 1) ? (w & 0xffff0000u) : (w << 16);
  return x.f;
}

// ---------------- prep0: dtype detect + bias + bc ----------------
__global__ void prep0(const void* b_enc, const void* b_ih, const void* b_hh,
                      const void* W1, float* ws) {
  __shared__ int anybig;
  int t = threadIdx.x;
  if (t == 0) anybig = 0;
  __syncthreads();
  {
    unsigned short u = ((const unsigned short*)b_enc)[t];
    float f = b2f((unsigned int)u);
    if (!(fabsf(f) <= 1.0f)) atomicOr(&anybig, 1);
  }
  __syncthreads();
  int b16 = anybig ? 0 : 1;
  if (t == 0) ((int*)ws)[0] = b16;
  for (int k = t; k < 1024; k += 256)
    ws[O_BIAS + k] = ldv(b_ih, b16, k) + ldv(b_hh, b16, k);
  if (t < 64) {
    float acc = 0.f;
    for (int h = 0; h < 256; ++h)
      acc += ldv(W1, b16, t * 256 + h) * ldv(b_enc, b16, h);
    ws[O_BC + t] = acc;
  }
}

// ---------------- prep1: Wc = W1 @ W_enc ----------------
__global__ void prep1(const void* W_enc, const void* W1, float* ws) {
  int b16 = ((const int*)ws)[0];
  int o = blockIdx.x * 256 + threadIdx.x;
  int w = o >> 7, i = o & 127;
  float acc = 0.f;
  for (int h = 0; h < 256; ++h)
    acc += ldv(W1, b16, w * 256 + h) * ldv(W_enc, b16, h * 128 + i);
  ws[O_WC + o] = acc;
}

// ---------------- wprep: hi/lo bf16 decomposition of W_hh, W_ih, W2 ----------------
// w = b2f(hi) + b2f(lo) represents w to ~2^-17 relative; MFMA on (hi,lo) pairs
// reproduces the fp32 product to ~1e-7 relative (all cross terms kept).
__global__ __launch_bounds__(256) void wprep(const void* W_ih, const void* W_hh,
                                             const void* W2, float* ws) {
  const int b16 = ((const int*)ws)[0];
  unsigned short* wb = (unsigned short*)(ws + O_WB);
  int i = blockIdx.x * 256 + threadIdx.x;
  if (i < 262144) {
    float w = ldv(W_hh, b16, i);
    unsigned short hi = f2b(w);
    wb[WB_HH_HI + i] = hi;
    wb[WB_HH_LO + i] = f2b(w - b2f((unsigned int)hi));
  }
  if (i < 131072) {
    float w = ldv(W_ih, b16, i);
    unsigned short hi = f2b(w);
    wb[WB_IH_HI + i] = hi;
    wb[WB_IH_LO + i] = f2b(w - b2f((unsigned int)hi));
  }
  if (i < 16384) {
    float w = ldv(W2, b16, i);
    unsigned short hi = f2b(w);
    wb[WB_W2_HI + i] = hi;
    wb[WB_W2_LO + i] = f2b(w - b2f((unsigned int)hi));
  }
}

// ---------------- blendk: blend1 = targets @ Wc^T + bc ----------------
__global__ __launch_bounds__(256) void blendk(const void* targets, float* ws) {
  __shared__ float tg[6400];
  __shared__ float wc[8192];
  int b16 = ((const int*)ws)[0];
  int t = threadIdx.x, b = blockIdx.x;
  for (int k = t; k < 8192; k += 256) wc[k] = ws[O_WC + k];
  if (b16) {
    const unsigned short* tp = (const unsigned short*)targets + (long long)b * 6400;
    for (int k = t * 8; k < 6400; k += 2048) {
      uint4 u = *(const uint4*)(tp + k);
      #pragma unroll
      for (int e = 0; e < 8; ++e) tg[k + e] = bfsel(u, e);
    }
  } else {
    const float* tp = (const float*)targets + (long long)b * 6400;
    for (int k = t; k < 6400; k += 256) tg[k] = tp[k];
  }
  __syncthreads();
  int w = t & 63, j0 = t >> 6;
  float bcv = ws[O_BC + w];
  for (int j = j0; j < 50; j += 4) {
    float acc = 0.f;
    for (int i0 = 0; i0 < 128; i0 += 8) {
      const float4* q = (const float4*)(wc + w * 128 + i0);
      float4 a = q[0], bb = q[1];
      const float* x = &tg[j * 128 + i0];
      acc += a.x * x[0] + a.y * x[1] + a.z * x[2] + a.w * x[3]
           + bb.x * x[4] + bb.y * x[5] + bb.z * x[6] + bb.w * x[7];
    }
    ws[O_BLEND1 + (b * 50 + j) * 64 + w] = acc + bcv;
  }
}

// ---------------- mainK: 50 steps, 4 batches/block, hi/lo MFMA GEMM ----------------
// A frag (16x32 per MFMA): rows 0-3 = hi of batches 0-3, rows 4-7 = lo, rows 8-15 = 0.
// Two MFMAs per fragment pair (B = W_hi, B = W_lo); D rows 0-3 (lanes 0-15) hold
// hi-side partials, rows 4-7 (lanes 16-31) lo-side; shfl_xor(16) sums them.
// Full product (x_hi+x_lo)(W_hi+W_lo) retained -> fp32-grade gates.
// Phases A2/C/argmax/D copied from the proven fp32 kernel.
__global__ __launch_bounds__(512, 2) void mainK(
    const void* targets, const void* h0, const void* c0, const void* vt,
    float* ws, void* outp) {
  __shared__ __align__(16) unsigned short hS[16][264];  // 0-3 hi, 4-7 lo, 8-15 zero
  __shared__ __align__(16) unsigned short xA[16][136];  // 0-3 hi, 4-7 lo, 8-15 zero
  __shared__ float cT[4][256];
  __shared__ float gsh[4][1024];
  __shared__ float bias_s[1024];
  __shared__ float b2s[4][64];
  __shared__ float outs[4][64];
  __shared__ float vt_s[64];
  __shared__ int   selidx[4];
  __shared__ int   selb[4][64];

  const int b16 = ((const int*)ws)[0];
  const int t = threadIdx.x;
  const int bbase = blockIdx.x * 4;
  const unsigned short* wb = (const unsigned short*)(ws + O_WB);
  const unsigned short* WhhH = wb + WB_HH_HI;
  const unsigned short* WhhL = wb + WB_HH_LO;
  const unsigned short* WihH = wb + WB_IH_HI;
  const unsigned short* WihL = wb + WB_IH_LO;
  const unsigned short* W2H  = wb + WB_W2_HI;
  const unsigned short* W2L  = wb + WB_W2_LO;

  for (int k = t; k < 1024; k += 512) bias_s[k] = ws[O_BIAS + k];
  if (t < 64) vt_s[t] = ldv(vt, b16, t);
  if (t < 256) selb[t >> 6][t & 63] = 0;
  if (t < 4) selidx[t] = -1;
  {
    unsigned short* z1 = &hS[0][0];
    unsigned short* z2 = &xA[0][0];
    for (int k = t; k < 16 * 264; k += 512) z1[k] = 0;
    for (int k = t; k < 16 * 136; k += 512) z2[k] = 0;
  }
  __syncthreads();
  for (int k = t; k < 1024; k += 512) {
    int p = k >> 8, j = k & 255;
    float h = ldv(h0, b16, (long long)(bbase + p) * 256 + j);
    float c = ldv(c0, b16, (long long)(bbase + p) * 256 + j);
    unsigned short hi = f2b(h);
    hS[p][j]     = hi;
    hS[p + 4][j] = f2b(h - b2f((unsigned int)hi));
    cT[p][j]     = c;
  }
  __syncthreads();

  const int l  = t & 63, Wv = t >> 6;   // lane, wave (0..7)
  const int lr = l & 15, lg = l >> 4;

  #pragma unroll 1
  for (int step = 0; step < 50; ++step) {
    // ---- phase A: gsh[p][g] = h@W_hh^T + x@W_ih^T (hi/lo MFMA, 8 tiles/wave) ----
    {
      bf16x8 ah[8], ax[4];
      #pragma unroll
      for (int kc = 0; kc < 8; ++kc)
        ah[kc] = *(const bf16x8*)&hS[lr][kc * 32 + lg * 8];
      #pragma unroll
      for (int kc = 0; kc < 4; ++kc)
        ax[kc] = *(const bf16x8*)&xA[lr][kc * 32 + lg * 8];
      #pragma unroll 2
      for (int ti = 0; ti < 8; ++ti) {
        const int nt = Wv * 8 + ti;                 // gate tile (16 rows of 1024)
        const int g0 = nt * 16 + lr;                // W row this lane supplies
        const unsigned short* whH = WhhH + (long long)g0 * 256 + lg * 8;
        const unsigned short* whL = WhhL + (long long)g0 * 256 + lg * 8;
        const unsigned short* wiH = WihH + (long long)g0 * 128 + lg * 8;
        const unsigned short* wiL = WihL + (long long)g0 * 128 + lg * 8;
        f32x4 aH = {0.f, 0.f, 0.f, 0.f};            // vs W_hi
        f32x4 aL = {0.f, 0.f, 0.f, 0.f};            // vs W_lo (independent chain)
        #pragma unroll
        for (int kc = 0; kc < 8; ++kc) {
          bf16x8 a = ah[kc];
          aH = mfma16(a, *(const bf16x8*)(whH + kc * 32), aH);
          aL = mfma16(a, *(const bf16x8*)(whL + kc * 32), aL);
        }
        #pragma unroll
        for (int kc = 0; kc < 4; ++kc) {
          bf16x8 a = ax[kc];
          aH = mfma16(a, *(const bf16x8*)(wiH + kc * 32), aH);
          aL = mfma16(a, *(const bf16x8*)(wiL + kc * 32), aL);
        }
        f32x4 acc = aH + aL;
        // hi partial (lanes 0-15) + lo partial (lanes 16-31)
        float s0 = acc[0] + __shfl_xor(acc[0], 16, 64);
        float s1 = acc[1] + __shfl_xor(acc[1], 16, 64);
        float s2 = acc[2] + __shfl_xor(acc[2], 16, 64);
        float s3 = acc[3] + __shfl_xor(acc[3], 16, 64);
        if (l < 16) {
          const int g = nt * 16 + l;
          gsh[0][g] = s0; gsh[1][g] = s1; gsh[2][g] = s2; gsh[3][g] = s3;
        }
      }
    }
    __syncthreads();

    // ---- phase A2: LSTM pointwise; h -> hi row p, lo row p+4 ----
    for (int k = t; k < 1024; k += 512) {
      int j = k & 255, p = k >> 8;
      float gi = sigm (gsh[p][j]       + bias_s[j]);
      float gf = sigm (gsh[p][256 + j] + bias_s[256 + j]);
      float gg = tanhx(gsh[p][512 + j] + bias_s[512 + j]);
      float go = sigm (gsh[p][768 + j] + bias_s[768 + j]);
      float c = gf * cT[p][j] + gi * gg;
      cT[p][j] = c;
      float h = go * tanhx(c);
      unsigned short hi = f2b(h);
      hS[p][j]     = hi;
      hS[p + 4][j] = f2b(h - b2f((unsigned int)hi));
    }
    __syncthreads();

    // ---- mini-pass: blend2 = h @ W2^T (hi/lo MFMA, waves 0-3, 1 tile each) ----
    if (Wv < 4) {
      bf16x8 bh[8];
      #pragma unroll
      for (int kc = 0; kc < 8; ++kc)
        bh[kc] = *(const bf16x8*)&hS[lr][kc * 32 + lg * 8];
      const int g0 = Wv * 16 + lr;
      const unsigned short* wpH = W2H + (long long)g0 * 256 + lg * 8;
      const unsigned short* wpL = W2L + (long long)g0 * 256 + lg * 8;
      f32x4 aH = {0.f, 0.f, 0.f, 0.f};
      f32x4 aL = {0.f, 0.f, 0.f, 0.f};
      #pragma unroll
      for (int kc = 0; kc < 8; ++kc) {
        bf16x8 a = bh[kc];
        aH = mfma16(a, *(const bf16x8*)(wpH + kc * 32), aH);
        aL = mfma16(a, *(const bf16x8*)(wpL + kc * 32), aL);
      }
      f32x4 acc = aH + aL;
      float s0 = acc[0] + __shfl_xor(acc[0], 16, 64);
      float s1 = acc[1] + __shfl_xor(acc[1], 16, 64);
      float s2 = acc[2] + __shfl_xor(acc[2], 16, 64);
      float s3 = acc[3] + __shfl_xor(acc[3], 16, 64);
      if (l < 16) {
        const int g = Wv * 16 + l;
        b2s[0][g] = s0; b2s[1][g] = s1; b2s[2][g] = s2; b2s[3][g] = s3;
      }
    }
    __syncthreads();

    // ---- phase C: out = vt . tanh(blend1 + blend2), mask ----
    if (t < 400) {
      int o = t >> 1, sp = t & 1;
      int p = o / 50, j = o - p * 50;
      const float* bl = ws + O_BLEND1 + (((bbase + p) * 50 + j) * 64) + sp * 32;
      float acc = 0.f;
      #pragma unroll 8
      for (int w = 0; w < 32; w++)
        acc += vt_s[sp * 32 + w] * tanhx(bl[w] + b2s[p][sp * 32 + w]);
      acc += __shfl_xor(acc, 1, 64);
      if (sp == 0) outs[p][j] = selb[p][j] ? NEG_INF_V : acc;
    }
    __syncthreads();

    // ---- argmax + softmax + write probs, update selected ----
    if (t < 256) {
      int p = t >> 6, lane = t & 63;
      float v = (lane < 50) ? outs[p][lane] : -3.4e38f;
      int idx = lane;
      #pragma unroll
      for (int msk = 1; msk < 64; msk <<= 1) {
        float ov = __shfl_xor(v, msk, 64);
        int   oi = __shfl_xor(idx, msk, 64);
        if (ov > v || (ov == v && oi < idx)) { v = ov; idx = oi; }
      }
      float e = (lane < 50) ? __expf(outs[p][lane] - v) : 0.f;
      float ssum = e;
      #pragma unroll
      for (int msk = 1; msk < 64; msk <<= 1) ssum += __shfl_xor(ssum, msk, 64);
      if (lane < 50) {
        float prob = fmaxf(e / ssum, 1e-9f);
        int o = (bbase + p) * 2500 + step * 50 + lane;
        if (b16) ((unsigned short*)outp)[o] = f2b(prob);
        else     ((float*)outp)[o] = prob;
      }
      if (lane == 0) selidx[p] = idx;
      if (lane == idx) selb[p][idx] = 1;
    }
    __syncthreads();

    // ---- phase D: dec_in gather; split x into hi/lo rows ----
    {
      int p = t >> 7, i = t & 127;
      float xf = ldv(targets, b16,
                     ((long long)(bbase + p) * 50 + selidx[p]) * 128 + i);
      unsigned short hi = f2b(xf);
      xA[p][i]     = hi;
      xA[p + 4][i] = f2b(xf - b2f((unsigned int)hi));
    }
    __syncthreads();
  }
}

extern "C" void kernel_launch(void* const* d_in, const int* in_sizes, int n_in,
                              void* d_out, int out_size, void* d_ws, size_t ws_size,
                              hipStream_t stream) {
  (void)in_sizes; (void)n_in; (void)out_size; (void)ws_size;
  const void* targets = d_in[0];
  const void* h0      = d_in[1];
  const void* c0      = d_in[2];
  const void* W_enc   = d_in[3];
  const void* b_enc   = d_in[4];
  const void* W_ih    = d_in[5];
  const void* W_hh    = d_in[6];
  const void* b_ih    = d_in[7];
  const void* b_hh    = d_in[8];
  const void* W1      = d_in[9];
  const void* W2      = d_in[10];
  const void* vt      = d_in[11];
  float* ws = (float*)d_ws;

  prep0<<<1, 256, 0, stream>>>(b_enc, b_ih, b_hh, W1, ws);
  prep1<<<32, 256, 0, stream>>>(W_enc, W1, ws);
  wprep<<<1024, 256, 0, stream>>>(W_ih, W_hh, W2, ws);
  blendk<<<1024, 256, 0, stream>>>(targets, ws);
  mainK<<<256, 512, 0, stream>>>(targets, h0, c0, vt, ws, d_out);
}

// Round 5
// 2308.716 us; speedup vs baseline: 1.1853x; 1.1853x over previous
//
#include <hip/hip_runtime.h>

// ---------------- ws layout (float offsets) ----------------
// [0]        : dtype flag (int: 1 = bf16 inputs, 0 = fp32 inputs)
// O_WC       : Wc = W1 @ W_enc   [64][128] fp32
// O_BC       : bc = W1 @ b_enc   [64] fp32
// O_BIAS     : bias = b_ih+b_hh  [1024] fp32
// O_BLEND1   : blend1 [1024][50][64] fp32
// O_WB       : packed hi/lo bf16 weights (ushort), tile-major wave-coalesced
#define O_WC     16
#define O_BC     (16 + 8192)
#define O_BIAS   (O_BC + 64)
#define O_BLEND1 16384
#define O_WB     3293184        // = 16384 + 1024*50*64
#define NEG_INF_V (-1.0e9f)

// packed weight region (ushort offsets).
// Gate tile nt (0..63) stride WB_TILE:
//   [0,4096)      hhH : kc(0..7)*512 + lane*8 + e
//   [4096,8192)   hhL
//   [8192,10240)  ihH : kc(0..3)*512 + lane*8 + e
//   [10240,12288) ihL
// W2 tile ntw (0..3) at WB_W2 + ntw*8192: [0,4096) hi, [4096,8192) lo.
#define WB_TILE 12288
#define WB_W2   786432

using bf16x8 = __attribute__((ext_vector_type(8))) __bf16;
using f32x4  = __attribute__((ext_vector_type(4))) float;

__device__ __forceinline__ f32x4 mfma16(bf16x8 a, bf16x8 b, f32x4 c) {
  return __builtin_amdgcn_mfma_f32_16x16x32_bf16(a, b, c, 0, 0, 0);
}

__device__ __forceinline__ float b2f(unsigned int u) {
  union { unsigned int i; float f; } x; x.i = u << 16; return x.f;
}
__device__ __forceinline__ unsigned short f2b(float f) {
  union { float f; unsigned int i; } x; x.f = f;
  unsigned int r = x.i + 0x7fffu + ((x.i >> 16) & 1u);
  return (unsigned short)(r >> 16);
}
__device__ __forceinline__ float ldv(const void* p, int b16, long long i) {
  if (b16) return b2f(((const unsigned short*)p)[i]);
  return ((const float*)p)[i];
}
__device__ __forceinline__ float sigm(float x)  { return 1.0f / (1.0f + __expf(-x)); }
__device__ __forceinline__ float tanhx(float x) { return 1.0f - 2.0f / (1.0f + __expf(2.0f * x)); }

// select bf16 element e (0..7) out of a uint4, e must be unroll-constant
__device__ __forceinline__ float bfsel(const uint4& u, int e) {
  unsigned int w = (e < 2) ? u.x : (e < 4) ? u.y : (e < 6) ? u.z : u.w;
  union { unsigned int i; float f; } x;
  x.i = (e & 1) ? (w & 0xffff0000u) : (w << 16);
  return x.f;
}

// ---------------- prep0: dtype detect + bias + bc ----------------
__global__ void prep0(const void* b_enc, const void* b_ih, const void* b_hh,
                      const void* W1, float* ws) {
  __shared__ int anybig;
  int t = threadIdx.x;
  if (t == 0) anybig = 0;
  __syncthreads();
  {
    unsigned short u = ((const unsigned short*)b_enc)[t];
    float f = b2f((unsigned int)u);
    if (!(fabsf(f) <= 1.0f)) atomicOr(&anybig, 1);
  }
  __syncthreads();
  int b16 = anybig ? 0 : 1;
  if (t == 0) ((int*)ws)[0] = b16;
  for (int k = t; k < 1024; k += 256)
    ws[O_BIAS + k] = ldv(b_ih, b16, k) + ldv(b_hh, b16, k);
  if (t < 64) {
    float acc = 0.f;
    for (int h = 0; h < 256; ++h)
      acc += ldv(W1, b16, t * 256 + h) * ldv(b_enc, b16, h);
    ws[O_BC + t] = acc;
  }
}

// ---------------- prep1: Wc = W1 @ W_enc ----------------
__global__ void prep1(const void* W_enc, const void* W1, float* ws) {
  int b16 = ((const int*)ws)[0];
  int o = blockIdx.x * 256 + threadIdx.x;
  int w = o >> 7, i = o & 127;
  float acc = 0.f;
  for (int h = 0; h < 256; ++h)
    acc += ldv(W1, b16, w * 256 + h) * ldv(W_enc, b16, h * 128 + i);
  ws[O_WC + o] = acc;
}

// ---------------- wprep: hi/lo decomposition into packed coalesced layout ------
// w = b2f(hi) + b2f(lo): ~2^-17 relative; MFMA over (hi,lo) pairs reproduces the
// fp32 product to ~1e-7. Destination lane l reads 16B at tile + kc*1KB + l*16B.
__global__ __launch_bounds__(256) void wprep(const void* W_ih, const void* W_hh,
                                             const void* W2, float* ws) {
  const int b16 = ((const int*)ws)[0];
  unsigned short* wb = (unsigned short*)(ws + O_WB);
  int i = blockIdx.x * 256 + threadIdx.x;          // grid covers 262144
  {  // W_hh [1024][256]
    int g = i >> 8, k = i & 255;
    int nt = g >> 4, r = g & 15;
    int kc = k >> 5, lane = ((k >> 3) & 3) * 16 + r, e = k & 7;
    float w = ldv(W_hh, b16, i);
    unsigned short hi = f2b(w);
    long long d = (long long)nt * WB_TILE + kc * 512 + lane * 8 + e;
    wb[d] = hi;
    wb[d + 4096] = f2b(w - b2f((unsigned int)hi));
  }
  if (i < 131072) {  // W_ih [1024][128]
    int g = i >> 7, k = i & 127;
    int nt = g >> 4, r = g & 15;
    int kc = k >> 5, lane = ((k >> 3) & 3) * 16 + r, e = k & 7;
    float w = ldv(W_ih, b16, i);
    unsigned short hi = f2b(w);
    long long d = (long long)nt * WB_TILE + 8192 + kc * 512 + lane * 8 + e;
    wb[d] = hi;
    wb[d + 2048] = f2b(w - b2f((unsigned int)hi));
  }
  if (i < 16384) {   // W2 [64][256]
    int g = i >> 8, k = i & 255;
    int ntw = g >> 4, r = g & 15;
    int kc = k >> 5, lane = ((k >> 3) & 3) * 16 + r, e = k & 7;
    float w = ldv(W2, b16, i);
    unsigned short hi = f2b(w);
    long long d = WB_W2 + ntw * 8192 + kc * 512 + lane * 8 + e;
    wb[d] = hi;
    wb[d + 4096] = f2b(w - b2f((unsigned int)hi));
  }
}

// ---------------- blendk: blend1 = targets @ Wc^T + bc ----------------
__global__ __launch_bounds__(256) void blendk(const void* targets, float* ws) {
  __shared__ float tg[6400];
  __shared__ float wc[8192];
  int b16 = ((const int*)ws)[0];
  int t = threadIdx.x, b = blockIdx.x;
  for (int k = t; k < 8192; k += 256) wc[k] = ws[O_WC + k];
  if (b16) {
    const unsigned short* tp = (const unsigned short*)targets + (long long)b * 6400;
    for (int k = t * 8; k < 6400; k += 2048) {
      uint4 u = *(const uint4*)(tp + k);
      #pragma unroll
      for (int e = 0; e < 8; ++e) tg[k + e] = bfsel(u, e);
    }
  } else {
    const float* tp = (const float*)targets + (long long)b * 6400;
    for (int k = t; k < 6400; k += 256) tg[k] = tp[k];
  }
  __syncthreads();
  int w = t & 63, j0 = t >> 6;
  float bcv = ws[O_BC + w];
  for (int j = j0; j < 50; j += 4) {
    float acc = 0.f;
    for (int i0 = 0; i0 < 128; i0 += 8) {
      const float4* q = (const float4*)(wc + w * 128 + i0);
      float4 a = q[0], bb = q[1];
      const float* x = &tg[j * 128 + i0];
      acc += a.x * x[0] + a.y * x[1] + a.z * x[2] + a.w * x[3]
           + bb.x * x[4] + bb.y * x[5] + bb.z * x[6] + bb.w * x[7];
    }
    ws[O_BLEND1 + (b * 50 + j) * 64 + w] = acc + bcv;
  }
}

// ---------------- mainK: 50 steps, 8 batches/block, hi/lo MFMA GEMM ----------------
// A rows 0-7 = h_hi (8 batches), rows 8-15 = h_lo; one MFMA per weight fragment
// serves all 8 batches; D lanes 0-31 = hi partials, 32-63 = lo; shfl_xor(32) sums.
// Per tile: 24 coalesced weight loads batched into regs, then 24 MFMAs.
// 128 blocks x 1024 threads (16 waves, 4 tiles/wave).
__global__ __launch_bounds__(1024, 2) void mainK(
    const void* targets, const void* h0, const void* c0, const void* vt,
    float* ws, void* outp) {
  __shared__ __align__(16) unsigned short hS[16][264];  // 0-7 hi, 8-15 lo
  __shared__ __align__(16) unsigned short xA[16][136];  // 0-7 hi, 8-15 lo
  __shared__ float cT[8][256];
  __shared__ float gsh[8][1024];
  __shared__ float bias_s[1024];
  __shared__ float b2s[8][64];
  __shared__ float outs[8][64];
  __shared__ float vt_s[64];
  __shared__ int   selidx[8];
  __shared__ int   selb[8][64];

  const int b16 = ((const int*)ws)[0];
  const int t = threadIdx.x;
  const int bbase = blockIdx.x * 8;
  const unsigned short* wb = (const unsigned short*)(ws + O_WB);

  bias_s[t] = ws[O_BIAS + t];
  if (t < 64) vt_s[t] = ldv(vt, b16, t);
  if (t < 512) selb[t >> 6][t & 63] = 0;
  if (t < 8) selidx[t] = -1;
  {
    unsigned short* z1 = &hS[0][0];
    unsigned short* z2 = &xA[0][0];
    for (int k = t; k < 16 * 264; k += 1024) z1[k] = 0;
    for (int k = t; k < 16 * 136; k += 1024) z2[k] = 0;
  }
  __syncthreads();
  for (int k = t; k < 2048; k += 1024) {
    int p = k >> 8, j = k & 255;
    float h = ldv(h0, b16, (long long)(bbase + p) * 256 + j);
    float c = ldv(c0, b16, (long long)(bbase + p) * 256 + j);
    unsigned short hi = f2b(h);
    hS[p][j]     = hi;
    hS[p + 8][j] = f2b(h - b2f((unsigned int)hi));
    cT[p][j]     = c;
  }
  __syncthreads();

  const int l  = t & 63, Wv = t >> 6;   // lane, wave (0..15)
  const int lr = l & 15;

  #pragma unroll 1
  for (int step = 0; step < 50; ++step) {
    // ---- phase A: gsh[p][g] = h@W_hh^T + x@W_ih^T (4 tiles/wave) ----
    {
      bf16x8 ah[8], ax[4];
      #pragma unroll
      for (int kc = 0; kc < 8; ++kc)
        ah[kc] = *(const bf16x8*)&hS[lr][kc * 32 + (l >> 4) * 8];
      #pragma unroll
      for (int kc = 0; kc < 4; ++kc)
        ax[kc] = *(const bf16x8*)&xA[lr][kc * 32 + (l >> 4) * 8];
      #pragma unroll 1
      for (int ti = 0; ti < 4; ++ti) {
        const int nt = Wv * 4 + ti;                 // gate tile (16 rows of 1024)
        const unsigned short* tb = wb + (long long)nt * WB_TILE + l * 8;
        // batch-issue all 24 coalesced weight loads into registers
        bf16x8 wH[12], wL[12];
        #pragma unroll
        for (int kc = 0; kc < 8; ++kc) {
          wH[kc] = *(const bf16x8*)(tb + kc * 512);
          wL[kc] = *(const bf16x8*)(tb + 4096 + kc * 512);
        }
        #pragma unroll
        for (int kc = 0; kc < 4; ++kc) {
          wH[8 + kc] = *(const bf16x8*)(tb + 8192 + kc * 512);
          wL[8 + kc] = *(const bf16x8*)(tb + 10240 + kc * 512);
        }
        f32x4 aH = {0.f, 0.f, 0.f, 0.f};
        f32x4 aL = {0.f, 0.f, 0.f, 0.f};
        #pragma unroll
        for (int kc = 0; kc < 8; ++kc) {
          aH = mfma16(ah[kc], wH[kc], aH);
          aL = mfma16(ah[kc], wL[kc], aL);
        }
        #pragma unroll
        for (int kc = 0; kc < 4; ++kc) {
          aH = mfma16(ax[kc], wH[8 + kc], aH);
          aL = mfma16(ax[kc], wL[8 + kc], aL);
        }
        __builtin_amdgcn_sched_group_barrier(0x020, 24, 0); // VMEM_READ x24 first
        __builtin_amdgcn_sched_group_barrier(0x008, 24, 0); // then MFMA x24
        f32x4 acc = aH + aL;
        // hi partials (lanes 0-31) + lo partials (lanes 32-63)
        float s0 = acc[0] + __shfl_xor(acc[0], 32, 64);
        float s1 = acc[1] + __shfl_xor(acc[1], 32, 64);
        float s2 = acc[2] + __shfl_xor(acc[2], 32, 64);
        float s3 = acc[3] + __shfl_xor(acc[3], 32, 64);
        if (l < 32) {
          const int g = nt * 16 + (l & 15), pb = (l >> 4) * 4;
          gsh[pb + 0][g] = s0; gsh[pb + 1][g] = s1;
          gsh[pb + 2][g] = s2; gsh[pb + 3][g] = s3;
        }
      }
    }
    __syncthreads();

    // ---- phase A2: LSTM pointwise; h -> hi row p, lo row p+8 ----
    for (int k = t; k < 2048; k += 1024) {
      int j = k & 255, p = k >> 8;
      float gi = sigm (gsh[p][j]       + bias_s[j]);
      float gf = sigm (gsh[p][256 + j] + bias_s[256 + j]);
      float gg = tanhx(gsh[p][512 + j] + bias_s[512 + j]);
      float go = sigm (gsh[p][768 + j] + bias_s[768 + j]);
      float c = gf * cT[p][j] + gi * gg;
      cT[p][j] = c;
      float h = go * tanhx(c);
      unsigned short hi = f2b(h);
      hS[p][j]     = hi;
      hS[p + 8][j] = f2b(h - b2f((unsigned int)hi));
    }
    __syncthreads();

    // ---- mini-pass: blend2 = h @ W2^T (waves 0-3, 1 tile each) ----
    if (Wv < 4) {
      bf16x8 bh[8];
      #pragma unroll
      for (int kc = 0; kc < 8; ++kc)
        bh[kc] = *(const bf16x8*)&hS[lr][kc * 32 + (l >> 4) * 8];
      const unsigned short* tb = wb + WB_W2 + Wv * 8192 + l * 8;
      bf16x8 wH[8], wL[8];
      #pragma unroll
      for (int kc = 0; kc < 8; ++kc) {
        wH[kc] = *(const bf16x8*)(tb + kc * 512);
        wL[kc] = *(const bf16x8*)(tb + 4096 + kc * 512);
      }
      f32x4 aH = {0.f, 0.f, 0.f, 0.f};
      f32x4 aL = {0.f, 0.f, 0.f, 0.f};
      #pragma unroll
      for (int kc = 0; kc < 8; ++kc) {
        aH = mfma16(bh[kc], wH[kc], aH);
        aL = mfma16(bh[kc], wL[kc], aL);
      }
      __builtin_amdgcn_sched_group_barrier(0x020, 16, 0);
      __builtin_amdgcn_sched_group_barrier(0x008, 16, 0);
      f32x4 acc = aH + aL;
      float s0 = acc[0] + __shfl_xor(acc[0], 32, 64);
      float s1 = acc[1] + __shfl_xor(acc[1], 32, 64);
      float s2 = acc[2] + __shfl_xor(acc[2], 32, 64);
      float s3 = acc[3] + __shfl_xor(acc[3], 32, 64);
      if (l < 32) {
        const int g = Wv * 16 + (l & 15), pb = (l >> 4) * 4;
        b2s[pb + 0][g] = s0; b2s[pb + 1][g] = s1;
        b2s[pb + 2][g] = s2; b2s[pb + 3][g] = s3;
      }
    }
    __syncthreads();

    // ---- phase C: out = vt . tanh(blend1 + blend2), mask (800 thr) ----
    if (t < 800) {
      int o = t >> 1, sp = t & 1;
      int p = o / 50, j = o - p * 50;
      const float* bl = ws + O_BLEND1 + (((bbase + p) * 50 + j) * 64) + sp * 32;
      float acc = 0.f;
      #pragma unroll
      for (int v4 = 0; v4 < 8; ++v4) {
        float4 bv = *(const float4*)(bl + v4 * 4);
        int w0 = sp * 32 + v4 * 4;
        acc += vt_s[w0 + 0] * tanhx(bv.x + b2s[p][w0 + 0]);
        acc += vt_s[w0 + 1] * tanhx(bv.y + b2s[p][w0 + 1]);
        acc += vt_s[w0 + 2] * tanhx(bv.z + b2s[p][w0 + 2]);
        acc += vt_s[w0 + 3] * tanhx(bv.w + b2s[p][w0 + 3]);
      }
      acc += __shfl_xor(acc, 1, 64);
      if (sp == 0) outs[p][j] = selb[p][j] ? NEG_INF_V : acc;
    }
    __syncthreads();

    // ---- argmax + softmax + write probs, update selected (8 waves) ----
    if (t < 512) {
      int p = t >> 6, lane = t & 63;
      float v = (lane < 50) ? outs[p][lane] : -3.4e38f;
      int idx = lane;
      #pragma unroll
      for (int msk = 1; msk < 64; msk <<= 1) {
        float ov = __shfl_xor(v, msk, 64);
        int   oi = __shfl_xor(idx, msk, 64);
        if (ov > v || (ov == v && oi < idx)) { v = ov; idx = oi; }
      }
      float e = (lane < 50) ? __expf(outs[p][lane] - v) : 0.f;
      float ssum = e;
      #pragma unroll
      for (int msk = 1; msk < 64; msk <<= 1) ssum += __shfl_xor(ssum, msk, 64);
      if (lane < 50) {
        float prob = fmaxf(e / ssum, 1e-9f);
        int o = (bbase + p) * 2500 + step * 50 + lane;
        if (b16) ((unsigned short*)outp)[o] = f2b(prob);
        else     ((float*)outp)[o] = prob;
      }
      if (lane == 0) selidx[p] = idx;
      if (lane == idx) selb[p][idx] = 1;
    }
    __syncthreads();

    // ---- phase D: dec_in gather; split x into hi/lo rows ----
    {
      int p = t >> 7, i = t & 127;
      float xf = ldv(targets, b16,
                     ((long long)(bbase + p) * 50 + selidx[p]) * 128 + i);
      unsigned short hi = f2b(xf);
      xA[p][i]     = hi;
      xA[p + 8][i] = f2b(xf - b2f((unsigned int)hi));
    }
    __syncthreads();
  }
}

extern "C" void kernel_launch(void* const* d_in, const int* in_sizes, int n_in,
                              void* d_out, int out_size, void* d_ws, size_t ws_size,
                              hipStream_t stream) {
  (void)in_sizes; (void)n_in; (void)out_size; (void)ws_size;
  const void* targets = d_in[0];
  const void* h0      = d_in[1];
  const void* c0      = d_in[2];
  const void* W_enc   = d_in[3];
  const void* b_enc   = d_in[4];
  const void* W_ih    = d_in[5];
  const void* W_hh    = d_in[6];
  const void* b_ih    = d_in[7];
  const void* b_hh    = d_in[8];
  const void* W1      = d_in[9];
  const void* W2      = d_in[10];
  const void* vt      = d_in[11];
  float* ws = (float*)d_ws;

  prep0<<<1, 256, 0, stream>>>(b_enc, b_ih, b_hh, W1, ws);
  prep1<<<32, 256, 0, stream>>>(W_enc, W1, ws);
  wprep<<<1024, 256, 0, stream>>>(W_ih, W_hh, W2, ws);
  blendk<<<1024, 256, 0, stream>>>(targets, ws);
  mainK<<<128, 1024, 0, stream>>>(targets, h0, c0, vt, ws, d_out);
}

// Round 6
// 1197.283 us; speedup vs baseline: 2.2855x; 1.9283x over previous
//
#include <hip/hip_runtime.h>

// ---------------- ws layout (float offsets) ----------------
// [0]        : dtype flag (int: 1 = bf16 inputs, 0 = fp32 inputs)
// O_WC       : Wc = W1 @ W_enc   [64][128] fp32
// O_BC       : bc = W1 @ b_enc   [64] fp32
// O_BIAS     : bias = b_ih+b_hh  [1024] fp32
// O_BLEND1   : blend1 [1024][50][64] fp32
// O_WB       : packed hi/lo bf16 weights (ushort), tile-major wave-coalesced
#define O_WC     16
#define O_BC     (16 + 8192)
#define O_BIAS   (O_BC + 64)
#define O_BLEND1 16384
#define O_WB     3293184        // = 16384 + 1024*50*64
#define NEG_INF_V (-1.0e9f)

// packed weight region (ushort offsets).
// Gate tile nt (0..63) stride WB_TILE:
//   [0,4096)      hhH : kc(0..7)*512 + lane*8 + e
//   [4096,8192)   hhL
//   [8192,10240)  ihH : kc(0..3)*512 + lane*8 + e
//   [10240,12288) ihL
// W2 tile ntw (0..3) at WB_W2 + ntw*8192: [0,4096) hi, [4096,8192) lo.
#define WB_TILE 12288
#define WB_W2   786432

using bf16x8 = __attribute__((ext_vector_type(8))) __bf16;
using f32x4  = __attribute__((ext_vector_type(4))) float;

__device__ __forceinline__ f32x4 mfma16(bf16x8 a, bf16x8 b, f32x4 c) {
  return __builtin_amdgcn_mfma_f32_16x16x32_bf16(a, b, c, 0, 0, 0);
}

__device__ __forceinline__ float b2f(unsigned int u) {
  union { unsigned int i; float f; } x; x.i = u << 16; return x.f;
}
__device__ __forceinline__ unsigned short f2b(float f) {
  union { float f; unsigned int i; } x; x.f = f;
  unsigned int r = x.i + 0x7fffu + ((x.i >> 16) & 1u);
  return (unsigned short)(r >> 16);
}
__device__ __forceinline__ float ldv(const void* p, int b16, long long i) {
  if (b16) return b2f(((const unsigned short*)p)[i]);
  return ((const float*)p)[i];
}
__device__ __forceinline__ float sigm(float x)  { return 1.0f / (1.0f + __expf(-x)); }
__device__ __forceinline__ float tanhx(float x) { return 1.0f - 2.0f / (1.0f + __expf(2.0f * x)); }

// select bf16 element e (0..7) out of a uint4, e must be unroll-constant
__device__ __forceinline__ float bfsel(const uint4& u, int e) {
  unsigned int w = (e < 2) ? u.x : (e < 4) ? u.y : (e < 6) ? u.z : u.w;
  union { unsigned int i; float f; } x;
  x.i = (e & 1) ? (w & 0xffff0000u) : (w << 16);
  return x.f;
}

// ---------------- prep0: dtype detect + bias + bc ----------------
__global__ void prep0(const void* b_enc, const void* b_ih, const void* b_hh,
                      const void* W1, float* ws) {
  __shared__ int anybig;
  int t = threadIdx.x;
  if (t == 0) anybig = 0;
  __syncthreads();
  {
    unsigned short u = ((const unsigned short*)b_enc)[t];
    float f = b2f((unsigned int)u);
    if (!(fabsf(f) <= 1.0f)) atomicOr(&anybig, 1);
  }
  __syncthreads();
  int b16 = anybig ? 0 : 1;
  if (t == 0) ((int*)ws)[0] = b16;
  for (int k = t; k < 1024; k += 256)
    ws[O_BIAS + k] = ldv(b_ih, b16, k) + ldv(b_hh, b16, k);
  if (t < 64) {
    float acc = 0.f;
    for (int h = 0; h < 256; ++h)
      acc += ldv(W1, b16, t * 256 + h) * ldv(b_enc, b16, h);
    ws[O_BC + t] = acc;
  }
}

// ---------------- prep1: Wc = W1 @ W_enc ----------------
__global__ void prep1(const void* W_enc, const void* W1, float* ws) {
  int b16 = ((const int*)ws)[0];
  int o = blockIdx.x * 256 + threadIdx.x;
  int w = o >> 7, i = o & 127;
  float acc = 0.f;
  for (int h = 0; h < 256; ++h)
    acc += ldv(W1, b16, w * 256 + h) * ldv(W_enc, b16, h * 128 + i);
  ws[O_WC + o] = acc;
}

// ---------------- wprep: hi/lo decomposition into packed coalesced layout ------
// w = b2f(hi) + b2f(lo): ~2^-17 relative; MFMA over (hi,lo) pairs reproduces the
// fp32 product to ~1e-7. Destination lane l reads 16B at tile + kc*1KB + l*16B.
__global__ __launch_bounds__(256) void wprep(const void* W_ih, const void* W_hh,
                                             const void* W2, float* ws) {
  const int b16 = ((const int*)ws)[0];
  unsigned short* wb = (unsigned short*)(ws + O_WB);
  int i = blockIdx.x * 256 + threadIdx.x;          // grid covers 262144
  {  // W_hh [1024][256]
    int g = i >> 8, k = i & 255;
    int nt = g >> 4, r = g & 15;
    int kc = k >> 5, lane = ((k >> 3) & 3) * 16 + r, e = k & 7;
    float w = ldv(W_hh, b16, i);
    unsigned short hi = f2b(w);
    long long d = (long long)nt * WB_TILE + kc * 512 + lane * 8 + e;
    wb[d] = hi;
    wb[d + 4096] = f2b(w - b2f((unsigned int)hi));
  }
  if (i < 131072) {  // W_ih [1024][128]
    int g = i >> 7, k = i & 127;
    int nt = g >> 4, r = g & 15;
    int kc = k >> 5, lane = ((k >> 3) & 3) * 16 + r, e = k & 7;
    float w = ldv(W_ih, b16, i);
    unsigned short hi = f2b(w);
    long long d = (long long)nt * WB_TILE + 8192 + kc * 512 + lane * 8 + e;
    wb[d] = hi;
    wb[d + 2048] = f2b(w - b2f((unsigned int)hi));
  }
  if (i < 16384) {   // W2 [64][256]
    int g = i >> 8, k = i & 255;
    int ntw = g >> 4, r = g & 15;
    int kc = k >> 5, lane = ((k >> 3) & 3) * 16 + r, e = k & 7;
    float w = ldv(W2, b16, i);
    unsigned short hi = f2b(w);
    long long d = WB_W2 + ntw * 8192 + kc * 512 + lane * 8 + e;
    wb[d] = hi;
    wb[d + 4096] = f2b(w - b2f((unsigned int)hi));
  }
}

// ---------------- blendk: blend1 = targets @ Wc^T + bc ----------------
__global__ __launch_bounds__(256) void blendk(const void* targets, float* ws) {
  __shared__ float tg[6400];
  __shared__ float wc[8192];
  int b16 = ((const int*)ws)[0];
  int t = threadIdx.x, b = blockIdx.x;
  for (int k = t; k < 8192; k += 256) wc[k] = ws[O_WC + k];
  if (b16) {
    const unsigned short* tp = (const unsigned short*)targets + (long long)b * 6400;
    for (int k = t * 8; k < 6400; k += 2048) {
      uint4 u = *(const uint4*)(tp + k);
      #pragma unroll
      for (int e = 0; e < 8; ++e) tg[k + e] = bfsel(u, e);
    }
  } else {
    const float* tp = (const float*)targets + (long long)b * 6400;
    for (int k = t; k < 6400; k += 256) tg[k] = tp[k];
  }
  __syncthreads();
  int w = t & 63, j0 = t >> 6;
  float bcv = ws[O_BC + w];
  for (int j = j0; j < 50; j += 4) {
    float acc = 0.f;
    for (int i0 = 0; i0 < 128; i0 += 8) {
      const float4* q = (const float4*)(wc + w * 128 + i0);
      float4 a = q[0], bb = q[1];
      const float* x = &tg[j * 128 + i0];
      acc += a.x * x[0] + a.y * x[1] + a.z * x[2] + a.w * x[3]
           + bb.x * x[4] + bb.y * x[5] + bb.z * x[6] + bb.w * x[7];
    }
    ws[O_BLEND1 + (b * 50 + j) * 64 + w] = acc + bcv;
  }
}

// ---------------- mainK: 50 steps, 8 batches/block, hi/lo MFMA GEMM ----------------
// A rows 0-7 = h_hi (8 batches), rows 8-15 = h_lo; one MFMA per weight fragment
// serves all 8 batches; D lanes 0-31 = hi partials, 32-63 = lo; shfl_xor(32) sums.
// Per tile: 24 coalesced weight loads batched into regs, then 24 MFMAs.
// 128 blocks x 512 threads (8 waves, 8 tiles/wave).
// amdgpu_waves_per_eu(2,2): pin exactly 2 waves/SIMD -> 256-VGPR budget, no spill
// (rounds 2/4/5 lesson: launch_bounds' 2nd arg makes LLVM chase 8 waves -> 64 VGPR
// -> scratch spill; pinning the range top stops that).
__global__ __launch_bounds__(512)
__attribute__((amdgpu_waves_per_eu(2, 2)))
void mainK(
    const void* targets, const void* h0, const void* c0, const void* vt,
    float* ws, void* outp) {
  __shared__ __align__(16) unsigned short hS[16][264];  // 0-7 hi, 8-15 lo
  __shared__ __align__(16) unsigned short xA[16][136];  // 0-7 hi, 8-15 lo
  __shared__ float cT[8][256];
  __shared__ float gsh[8][1024];
  __shared__ float bias_s[1024];
  __shared__ float b2s[8][64];
  __shared__ float outs[8][64];
  __shared__ float vt_s[64];
  __shared__ int   selidx[8];
  __shared__ int   selb[8][64];

  const int b16 = ((const int*)ws)[0];
  const int t = threadIdx.x;
  const int bbase = blockIdx.x * 8;
  const unsigned short* wb = (const unsigned short*)(ws + O_WB);

  for (int k = t; k < 1024; k += 512) bias_s[k] = ws[O_BIAS + k];
  if (t < 64) vt_s[t] = ldv(vt, b16, t);
  if (t < 512) selb[t >> 6][t & 63] = 0;
  if (t < 8) selidx[t] = -1;
  {
    unsigned short* z1 = &hS[0][0];
    unsigned short* z2 = &xA[0][0];
    for (int k = t; k < 16 * 264; k += 512) z1[k] = 0;
    for (int k = t; k < 16 * 136; k += 512) z2[k] = 0;
  }
  __syncthreads();
  for (int k = t; k < 2048; k += 512) {
    int p = k >> 8, j = k & 255;
    float h = ldv(h0, b16, (long long)(bbase + p) * 256 + j);
    float c = ldv(c0, b16, (long long)(bbase + p) * 256 + j);
    unsigned short hi = f2b(h);
    hS[p][j]     = hi;
    hS[p + 8][j] = f2b(h - b2f((unsigned int)hi));
    cT[p][j]     = c;
  }
  __syncthreads();

  const int l  = t & 63, Wv = t >> 6;   // lane, wave (0..7)
  const int lr = l & 15;

  #pragma unroll 1
  for (int step = 0; step < 50; ++step) {
    // ---- phase A: gsh[p][g] = h@W_hh^T + x@W_ih^T (8 tiles/wave) ----
    {
      bf16x8 ah[8], ax[4];
      #pragma unroll
      for (int kc = 0; kc < 8; ++kc)
        ah[kc] = *(const bf16x8*)&hS[lr][kc * 32 + (l >> 4) * 8];
      #pragma unroll
      for (int kc = 0; kc < 4; ++kc)
        ax[kc] = *(const bf16x8*)&xA[lr][kc * 32 + (l >> 4) * 8];
      #pragma unroll 1
      for (int ti = 0; ti < 8; ++ti) {
        const int nt = Wv * 8 + ti;                 // gate tile (16 rows of 1024)
        const unsigned short* tb = wb + (long long)nt * WB_TILE + l * 8;
        // batch-issue all 24 coalesced weight loads into registers
        bf16x8 wH[12], wL[12];
        #pragma unroll
        for (int kc = 0; kc < 8; ++kc) {
          wH[kc] = *(const bf16x8*)(tb + kc * 512);
          wL[kc] = *(const bf16x8*)(tb + 4096 + kc * 512);
        }
        #pragma unroll
        for (int kc = 0; kc < 4; ++kc) {
          wH[8 + kc] = *(const bf16x8*)(tb + 8192 + kc * 512);
          wL[8 + kc] = *(const bf16x8*)(tb + 10240 + kc * 512);
        }
        f32x4 aH = {0.f, 0.f, 0.f, 0.f};
        f32x4 aL = {0.f, 0.f, 0.f, 0.f};
        #pragma unroll
        for (int kc = 0; kc < 8; ++kc) {
          aH = mfma16(ah[kc], wH[kc], aH);
          aL = mfma16(ah[kc], wL[kc], aL);
        }
        #pragma unroll
        for (int kc = 0; kc < 4; ++kc) {
          aH = mfma16(ax[kc], wH[8 + kc], aH);
          aL = mfma16(ax[kc], wL[8 + kc], aL);
        }
        __builtin_amdgcn_sched_group_barrier(0x020, 24, 0); // VMEM_READ x24 first
        __builtin_amdgcn_sched_group_barrier(0x008, 24, 0); // then MFMA x24
        f32x4 acc = aH + aL;
        // hi partials (lanes 0-31) + lo partials (lanes 32-63)
        float s0 = acc[0] + __shfl_xor(acc[0], 32, 64);
        float s1 = acc[1] + __shfl_xor(acc[1], 32, 64);
        float s2 = acc[2] + __shfl_xor(acc[2], 32, 64);
        float s3 = acc[3] + __shfl_xor(acc[3], 32, 64);
        if (l < 32) {
          const int g = nt * 16 + (l & 15), pb = (l >> 4) * 4;
          gsh[pb + 0][g] = s0; gsh[pb + 1][g] = s1;
          gsh[pb + 2][g] = s2; gsh[pb + 3][g] = s3;
        }
      }
    }
    __syncthreads();

    // ---- phase A2: LSTM pointwise; h -> hi row p, lo row p+8 ----
    for (int k = t; k < 2048; k += 512) {
      int j = k & 255, p = k >> 8;
      float gi = sigm (gsh[p][j]       + bias_s[j]);
      float gf = sigm (gsh[p][256 + j] + bias_s[256 + j]);
      float gg = tanhx(gsh[p][512 + j] + bias_s[512 + j]);
      float go = sigm (gsh[p][768 + j] + bias_s[768 + j]);
      float c = gf * cT[p][j] + gi * gg;
      cT[p][j] = c;
      float h = go * tanhx(c);
      unsigned short hi = f2b(h);
      hS[p][j]     = hi;
      hS[p + 8][j] = f2b(h - b2f((unsigned int)hi));
    }
    __syncthreads();

    // ---- mini-pass: blend2 = h @ W2^T (waves 0-3, 1 tile each) ----
    if (Wv < 4) {
      bf16x8 bh[8];
      #pragma unroll
      for (int kc = 0; kc < 8; ++kc)
        bh[kc] = *(const bf16x8*)&hS[lr][kc * 32 + (l >> 4) * 8];
      const unsigned short* tb = wb + WB_W2 + Wv * 8192 + l * 8;
      bf16x8 wH[8], wL[8];
      #pragma unroll
      for (int kc = 0; kc < 8; ++kc) {
        wH[kc] = *(const bf16x8*)(tb + kc * 512);
        wL[kc] = *(const bf16x8*)(tb + 4096 + kc * 512);
      }
      f32x4 aH = {0.f, 0.f, 0.f, 0.f};
      f32x4 aL = {0.f, 0.f, 0.f, 0.f};
      #pragma unroll
      for (int kc = 0; kc < 8; ++kc) {
        aH = mfma16(bh[kc], wH[kc], aH);
        aL = mfma16(bh[kc], wL[kc], aL);
      }
      __builtin_amdgcn_sched_group_barrier(0x020, 16, 0);
      __builtin_amdgcn_sched_group_barrier(0x008, 16, 0);
      f32x4 acc = aH + aL;
      float s0 = acc[0] + __shfl_xor(acc[0], 32, 64);
      float s1 = acc[1] + __shfl_xor(acc[1], 32, 64);
      float s2 = acc[2] + __shfl_xor(acc[2], 32, 64);
      float s3 = acc[3] + __shfl_xor(acc[3], 32, 64);
      if (l < 32) {
        const int g = Wv * 16 + (l & 15), pb = (l >> 4) * 4;
        b2s[pb + 0][g] = s0; b2s[pb + 1][g] = s1;
        b2s[pb + 2][g] = s2; b2s[pb + 3][g] = s3;
      }
    }
    __syncthreads();

    // ---- phase C: out = vt . tanh(blend1 + blend2), mask (1 thr/row) ----
    if (t < 400) {
      int p = t / 50, j = t - p * 50;
      const float* bl = ws + O_BLEND1 + (((bbase + p) * 50 + j) * 64);
      float acc = 0.f;
      #pragma unroll
      for (int v4 = 0; v4 < 16; ++v4) {
        float4 bv = *(const float4*)(bl + v4 * 4);
        int w0 = v4 * 4;
        acc += vt_s[w0 + 0] * tanhx(bv.x + b2s[p][w0 + 0]);
        acc += vt_s[w0 + 1] * tanhx(bv.y + b2s[p][w0 + 1]);
        acc += vt_s[w0 + 2] * tanhx(bv.z + b2s[p][w0 + 2]);
        acc += vt_s[w0 + 3] * tanhx(bv.w + b2s[p][w0 + 3]);
      }
      outs[p][j] = selb[p][j] ? NEG_INF_V : acc;
    }
    __syncthreads();

    // ---- argmax + softmax + write probs, update selected (8 waves) ----
    {
      int p = Wv, lane = l;
      float v = (lane < 50) ? outs[p][lane] : -3.4e38f;
      int idx = lane;
      #pragma unroll
      for (int msk = 1; msk < 64; msk <<= 1) {
        float ov = __shfl_xor(v, msk, 64);
        int   oi = __shfl_xor(idx, msk, 64);
        if (ov > v || (ov == v && oi < idx)) { v = ov; idx = oi; }
      }
      float e = (lane < 50) ? __expf(outs[p][lane] - v) : 0.f;
      float ssum = e;
      #pragma unroll
      for (int msk = 1; msk < 64; msk <<= 1) ssum += __shfl_xor(ssum, msk, 64);
      if (lane < 50) {
        float prob = fmaxf(e / ssum, 1e-9f);
        int o = (bbase + p) * 2500 + step * 50 + lane;
        if (b16) ((unsigned short*)outp)[o] = f2b(prob);
        else     ((float*)outp)[o] = prob;
      }
      if (lane == 0) selidx[p] = idx;
      if (lane == idx) selb[p][idx] = 1;
    }
    __syncthreads();

    // ---- phase D: dec_in gather; split x into hi/lo rows ----
    for (int k = t; k < 1024; k += 512) {
      int p = k >> 7, i = k & 127;
      float xf = ldv(targets, b16,
                     ((long long)(bbase + p) * 50 + selidx[p]) * 128 + i);
      unsigned short hi = f2b(xf);
      xA[p][i]     = hi;
      xA[p + 8][i] = f2b(xf - b2f((unsigned int)hi));
    }
    __syncthreads();
  }
}

extern "C" void kernel_launch(void* const* d_in, const int* in_sizes, int n_in,
                              void* d_out, int out_size, void* d_ws, size_t ws_size,
                              hipStream_t stream) {
  (void)in_sizes; (void)n_in; (void)out_size; (void)ws_size;
  const void* targets = d_in[0];
  const void* h0      = d_in[1];
  const void* c0      = d_in[2];
  const void* W_enc   = d_in[3];
  const void* b_enc   = d_in[4];
  const void* W_ih    = d_in[5];
  const void* W_hh    = d_in[6];
  const void* b_ih    = d_in[7];
  const void* b_hh    = d_in[8];
  const void* W1      = d_in[9];
  const void* W2      = d_in[10];
  const void* vt      = d_in[11];
  float* ws = (float*)d_ws;

  prep0<<<1, 256, 0, stream>>>(b_enc, b_ih, b_hh, W1, ws);
  prep1<<<32, 256, 0, stream>>>(W_enc, W1, ws);
  wprep<<<1024, 256, 0, stream>>>(W_ih, W_hh, W2, ws);
  blendk<<<1024, 256, 0, stream>>>(targets, ws);
  mainK<<<128, 512, 0, stream>>>(targets, h0, c0, vt, ws, d_out);
}